// Round 1
// baseline (517.225 us; speedup 1.0000x reference)
//
#include <hip/hip_runtime.h>

// Quaternion + scale -> 3x3 covariance, N = 8e6 gaussians.
// Memory-bound: 28 B in + 36 B out per gaussian = 512 MB total -> ~81 us floor @ 6.3 TB/s.
// Each thread handles 4 gaussians so ALL global traffic is float4 (16 B/lane):
//   quat:  4 x float4   (byte base 64g, aligned)
//   scale: 3 x float4   (byte base 48g, aligned)
//   cov:   9 x float4   (byte base 144g, aligned)

__global__ __launch_bounds__(256) void gauss_cov_kernel(
    const float* __restrict__ rot,    // (N,4)
    const float* __restrict__ scl,    // (N,3)
    float* __restrict__ out,          // (N,3,3)
    int ngroups,                      // N/4
    int rem_base, int rem)            // tail elements (N % 4), handled scalar
{
    const int stride = gridDim.x * blockDim.x;
    for (int g = blockIdx.x * blockDim.x + threadIdx.x; g < ngroups; g += stride) {
        // ---- loads: all float4 ----
        const float4* rq = reinterpret_cast<const float4*>(rot) + 4 * (size_t)g;
        float4 q0 = rq[0], q1 = rq[1], q2 = rq[2], q3 = rq[3];
        const float4* rs = reinterpret_cast<const float4*>(scl + 12 * (size_t)g);
        float4 s0 = rs[0], s1 = rs[1], s2 = rs[2];

        float qw[4] = {q0.x, q1.x, q2.x, q3.x};
        float qx[4] = {q0.y, q1.y, q2.y, q3.y};
        float qy[4] = {q0.z, q1.z, q2.z, q3.z};
        float qz[4] = {q0.w, q1.w, q2.w, q3.w};
        float sa[4] = {s0.x, s0.w, s1.z, s2.y};
        float sb[4] = {s0.y, s1.x, s1.w, s2.z};
        float sc[4] = {s0.z, s1.y, s2.x, s2.w};

        float o[36];
        #pragma unroll
        for (int i = 0; i < 4; ++i) {
            float w = qw[i], x = qx[i], y = qy[i], z = qz[i];
            float d = w * w + x * x + y * y + z * z;
            float inv = 1.0f / sqrtf(d);      // precise; compute is free here
            w *= inv; x *= inv; y *= inv; z *= inv;

            float R00 = 1.f - 2.f * (y * y + z * z);
            float R01 = 2.f * (x * y - w * z);
            float R02 = 2.f * (x * z + w * y);
            float R10 = 2.f * (x * y + w * z);
            float R11 = 1.f - 2.f * (x * x + z * z);
            float R12 = 2.f * (y * z - w * x);
            float R20 = 2.f * (x * z - w * y);
            float R21 = 2.f * (y * z + w * x);
            float R22 = 1.f - 2.f * (x * x + y * y);

            float a = sa[i] * sa[i], b = sb[i] * sb[i], c = sc[i] * sc[i];

            // cov = (R * diag(s)) (R * diag(s))^T ; symmetric, 6 unique entries
            float c00 = R00 * R00 * a + R01 * R01 * b + R02 * R02 * c;
            float c01 = R00 * R10 * a + R01 * R11 * b + R02 * R12 * c;
            float c02 = R00 * R20 * a + R01 * R21 * b + R02 * R22 * c;
            float c11 = R10 * R10 * a + R11 * R11 * b + R12 * R12 * c;
            float c12 = R10 * R20 * a + R11 * R21 * b + R12 * R22 * c;
            float c22 = R20 * R20 * a + R21 * R21 * b + R22 * R22 * c;

            float* oi = o + 9 * i;
            oi[0] = c00; oi[1] = c01; oi[2] = c02;
            oi[3] = c01; oi[4] = c11; oi[5] = c12;
            oi[6] = c02; oi[7] = c12; oi[8] = c22;
        }

        // ---- store: 9 x float4, fully contiguous 144 B per thread ----
        float4* o4 = reinterpret_cast<float4*>(out + 36 * (size_t)g);
        const float4* src = reinterpret_cast<const float4*>(o);
        #pragma unroll
        for (int j = 0; j < 9; ++j) o4[j] = src[j];
    }

    // scalar tail (N % 4) — N=8e6 makes rem==0, kept for generality
    if (blockIdx.x == 0 && (int)threadIdx.x < rem) {
        int e = rem_base + threadIdx.x;
        float w = rot[4 * (size_t)e + 0], x = rot[4 * (size_t)e + 1];
        float y = rot[4 * (size_t)e + 2], z = rot[4 * (size_t)e + 3];
        float inv = 1.0f / sqrtf(w * w + x * x + y * y + z * z);
        w *= inv; x *= inv; y *= inv; z *= inv;
        float R00 = 1.f - 2.f * (y * y + z * z), R01 = 2.f * (x * y - w * z), R02 = 2.f * (x * z + w * y);
        float R10 = 2.f * (x * y + w * z), R11 = 1.f - 2.f * (x * x + z * z), R12 = 2.f * (y * z - w * x);
        float R20 = 2.f * (x * z - w * y), R21 = 2.f * (y * z + w * x), R22 = 1.f - 2.f * (x * x + y * y);
        float a = scl[3 * (size_t)e + 0]; a *= a;
        float b = scl[3 * (size_t)e + 1]; b *= b;
        float c = scl[3 * (size_t)e + 2]; c *= c;
        float* oi = out + 9 * (size_t)e;
        float c00 = R00 * R00 * a + R01 * R01 * b + R02 * R02 * c;
        float c01 = R00 * R10 * a + R01 * R11 * b + R02 * R12 * c;
        float c02 = R00 * R20 * a + R01 * R21 * b + R02 * R22 * c;
        float c11 = R10 * R10 * a + R11 * R11 * b + R12 * R12 * c;
        float c12 = R10 * R20 * a + R11 * R21 * b + R12 * R22 * c;
        float c22 = R20 * R20 * a + R21 * R21 * b + R22 * R22 * c;
        oi[0] = c00; oi[1] = c01; oi[2] = c02;
        oi[3] = c01; oi[4] = c11; oi[5] = c12;
        oi[6] = c02; oi[7] = c12; oi[8] = c22;
    }
}

extern "C" void kernel_launch(void* const* d_in, const int* in_sizes, int n_in,
                              void* d_out, int out_size, void* d_ws, size_t ws_size,
                              hipStream_t stream) {
    const float* rot = (const float*)d_in[0];   // (N,4) f32
    const float* scl = (const float*)d_in[1];   // (N,3) f32
    float* out = (float*)d_out;                 // (N,3,3) f32

    const int n = in_sizes[0] / 4;              // N
    const int ngroups = n / 4;
    const int rem = n - 4 * ngroups;
    const int rem_base = 4 * ngroups;

    // 2048 blocks x 256 threads = 8 blocks/CU x 256 CU resident; grid-stride the rest.
    int grid = (ngroups + 255) / 256;
    if (grid > 2048) grid = 2048;
    if (grid < 1) grid = 1;

    gauss_cov_kernel<<<grid, 256, 0, stream>>>(rot, scl, out, ngroups, rem_base, rem);
}

// Round 3
// 418.904 us; speedup vs baseline: 1.2347x; 1.2347x over previous
//
#include <hip/hip_runtime.h>

// Quaternion + scale -> 3x3 covariance, N = 8e6 gaussians. Memory-bound:
// ideal 28 B in + 36 B out per gaussian = 512 MB total -> ~81 us @ 6.3 TB/s.
//
// Round-1 lesson: per-thread-contiguous stores (144 B lane stride) caused
// 1.75x HBM write amplification (partial-line sectored writes) and capped BW
// at 40%. This version makes EVERY global access unit-stride across lanes:
//   - quat:  1 thread = 1 gaussian, lane i loads float4 #i     (coalesced)
//   - scale: 3 coalesced dword loads -> LDS -> per-thread read (2-way bank, free)
//   - cov:   9 floats -> LDS, barrier, block region stored as
//            576 consecutive float4 (lane i -> 16B slot i)     (coalesced)

constexpr int BLK = 256;

__global__ __launch_bounds__(256) void gauss_cov_kernel(
    const float* __restrict__ rot,   // (N,4)
    const float* __restrict__ scl,   // (N,3)
    float* __restrict__ out,         // (N,3,3) = (N,9)
    int n)
{
    __shared__ float s_scl[3 * BLK];   // 3072 B
    __shared__ float s_out[9 * BLK];   // 9216 B

    const size_t base = (size_t)blockIdx.x * BLK;
    const int t = threadIdx.x;
    const size_t g = base + t;
    const int valid = (int)((n - (long long)base < BLK) ? (n - (long long)base) : BLK);

    // ---- stage scale: 3*valid floats, unit-stride across lanes ----
    for (int j = t; j < 3 * valid; j += BLK)
        s_scl[j] = scl[3 * base + j];

    // ---- quat: naturally one float4 per gaussian, coalesced ----
    float4 q = make_float4(1.f, 0.f, 0.f, 0.f);
    if (g < (size_t)n) q = reinterpret_cast<const float4*>(rot)[g];

    __syncthreads();

    if (t < valid) {
        float w = q.x, x = q.y, y = q.z, z = q.w;
        float inv = 1.0f / sqrtf(w * w + x * x + y * y + z * z);
        w *= inv; x *= inv; y *= inv; z *= inv;

        float R00 = 1.f - 2.f * (y * y + z * z);
        float R01 = 2.f * (x * y - w * z);
        float R02 = 2.f * (x * z + w * y);
        float R10 = 2.f * (x * y + w * z);
        float R11 = 1.f - 2.f * (x * x + z * z);
        float R12 = 2.f * (y * z - w * x);
        float R20 = 2.f * (x * z - w * y);
        float R21 = 2.f * (y * z + w * x);
        float R22 = 1.f - 2.f * (x * x + y * y);

        float a = s_scl[3 * t + 0]; a *= a;
        float b = s_scl[3 * t + 1]; b *= b;
        float c = s_scl[3 * t + 2]; c *= c;

        // cov = (R diag(s)) (R diag(s))^T — symmetric, 6 unique entries
        float c00 = R00 * R00 * a + R01 * R01 * b + R02 * R02 * c;
        float c01 = R00 * R10 * a + R01 * R11 * b + R02 * R12 * c;
        float c02 = R00 * R20 * a + R01 * R21 * b + R02 * R22 * c;
        float c11 = R10 * R10 * a + R11 * R11 * b + R12 * R12 * c;
        float c12 = R10 * R20 * a + R11 * R21 * b + R12 * R22 * c;
        float c22 = R20 * R20 * a + R21 * R21 * b + R22 * R22 * c;

        float* o = s_out + 9 * t;       // stride-9 write: 2-way bank alias, free
        o[0] = c00; o[1] = c01; o[2] = c02;
        o[3] = c01; o[4] = c11; o[5] = c12;
        o[6] = c02; o[7] = c12; o[8] = c22;
    }

    __syncthreads();

    // ---- store: block's 9216 B as 576 consecutive float4, coalesced ----
    if (valid == BLK) {
        float4* ob = reinterpret_cast<float4*>(out + 9 * base);
        const float4* sb = reinterpret_cast<const float4*>(s_out);
        ob[t]       = sb[t];
        ob[t + 256] = sb[t + 256];
        if (t < 64) ob[t + 512] = sb[t + 512];
    } else {
        for (int j = t; j < 9 * valid; j += BLK)
            out[9 * base + j] = s_out[j];
    }
}

extern "C" void kernel_launch(void* const* d_in, const int* in_sizes, int n_in,
                              void* d_out, int out_size, void* d_ws, size_t ws_size,
                              hipStream_t stream) {
    const float* rot = (const float*)d_in[0];   // (N,4) f32
    const float* scl = (const float*)d_in[1];   // (N,3) f32
    float* out = (float*)d_out;                 // (N,9) f32

    const int n = in_sizes[0] / 4;              // N
    const int grid = (n + BLK - 1) / BLK;       // 31250 blocks at N=8e6

    gauss_cov_kernel<<<grid, BLK, 0, stream>>>(rot, scl, out, n);
}